// Round 4
// baseline (49.050 us; speedup 1.0000x reference)
//
#include <hip/hip_runtime.h>
#include <hip/hip_bf16.h>

// Problem constants
#define B 64
#define D 1024
#define H 1024
#define C 32           // number of chunks along D
#define L (D / C)      // chunk length = 32
#define BG 2           // batch rows per block (register-shared weight loads)
#define NBG (B / BG)   // 32 batch groups

// DPP quad-perm cross-lane (VALU-speed, no LDS)
__device__ __forceinline__ float dpp_xor1(float v) {
    int i = __builtin_bit_cast(int, v);
    i = __builtin_amdgcn_mov_dpp(i, 0xB1, 0xF, 0xF, true);  // quad_perm [1,0,3,2]
    return __builtin_bit_cast(float, i);
}
__device__ __forceinline__ float dpp_xor2(float v) {
    int i = __builtin_bit_cast(int, v);
    i = __builtin_amdgcn_mov_dpp(i, 0x4E, 0xF, 0xF, true);  // quad_perm [2,3,0,1]
    return __builtin_bit_cast(float, i);
}

// ---------------------------------------------------------------------------
// Kernel 0: transpose in_W [H, D] -> Wt [D, H]
// ---------------------------------------------------------------------------
__global__ void k_transpose(const float* __restrict__ in, float* __restrict__ out) {
    __shared__ float tile[32][33];
    int bx = blockIdx.x * 32;  // d-range
    int by = blockIdx.y * 32;  // h-range
    int tx = threadIdx.x;      // 0..31
    int ty = threadIdx.y;      // 0..7
    #pragma unroll
    for (int r = 0; r < 32; r += 8)
        tile[ty + r][tx] = in[(by + ty + r) * D + (bx + tx)];
    __syncthreads();
    #pragma unroll
    for (int r = 0; r < 32; r += 8)
        out[(bx + ty + r) * H + (by + tx)] = tile[tx][ty + r];
}

// ---------------------------------------------------------------------------
// Kernel 1: per-chunk rank-1 sums, BG=2 batch rows per block (register reuse).
// block = (bg,c): S[b,c,:] = sum_{j in chunk c} x[b,j]*Wt[j,:]  (x in {0,1})
// ---------------------------------------------------------------------------
__global__ void __launch_bounds__(256, 4)
k_chunk_sums(const float* __restrict__ x,
             const float* __restrict__ Wt,
             float* __restrict__ S) {
    int blk = blockIdx.x;
    int bg = blk / C;
    int c  = blk % C;
    int b0 = bg * BG;
    int tid = threadIdx.x;
    int h0 = tid * 4;

    // x bitmasks for the two rows via one wave-0 ballot
    __shared__ unsigned mlds[BG];
    float xv = (tid < BG * L) ? x[(size_t)(b0 + (tid >> 5)) * D + c * L + (tid & 31)] : 0.f;
    unsigned long long bal = __ballot(xv != 0.f);
    if (tid == 0) { mlds[0] = (unsigned)bal; mlds[1] = (unsigned)(bal >> 32); }
    __syncthreads();
    unsigned m0 = mlds[0], m1 = mlds[1];
    unsigned any = m0 | m1;

    float4 acc0 = make_float4(0.f, 0.f, 0.f, 0.f);
    float4 acc1 = make_float4(0.f, 0.f, 0.f, 0.f);
    #pragma unroll
    for (int j = 0; j < L; ++j) {
        unsigned bit = 1u << j;
        if (any & bit) {   // wave-uniform
            float4 w = *reinterpret_cast<const float4*>(&Wt[(size_t)(c * L + j) * H + h0]);
            if (m0 & bit) { acc0.x += w.x; acc0.y += w.y; acc0.z += w.z; acc0.w += w.w; }
            if (m1 & bit) { acc1.x += w.x; acc1.y += w.y; acc1.z += w.z; acc1.w += w.w; }
        }
    }
    *reinterpret_cast<float4*>(&S[((size_t)b0 * C + c) * H + h0]) = acc0;
    *reinterpret_cast<float4*>(&S[((size_t)(b0 + 1) * C + c) * H + h0]) = acc1;
}

// ---------------------------------------------------------------------------
// Kernel 2: in-place exclusive scan over chunks
// ---------------------------------------------------------------------------
__global__ void k_scan(float* __restrict__ S) {
    int tid = blockIdx.x * blockDim.x + threadIdx.x;  // 0 .. B*H-1
    if (tid >= B * H) return;
    int b = tid / H;
    int h = tid % H;
    float run = 0.f;
    #pragma unroll
    for (int c = 0; c < C; ++c) {
        int idx = (b * C + c) * H + h;
        float v = S[idx];
        S[idx] = run;
        run += v;
    }
}

// ---------------------------------------------------------------------------
// Kernel 3: main NADE chain, BG=2 rows per block, barrier-free deferred
// reduction. block = (bg,c), 256 threads, 4 h per thread. One h_W/Wt float4
// load feeds both batch rows (register reuse -> halves L1+L2 traffic).
// ---------------------------------------------------------------------------
__global__ void __launch_bounds__(256, 4)
k_nade_main(const float* __restrict__ x,
            const float* __restrict__ Wt,
            const float* __restrict__ in_b,
            const float* __restrict__ h_W,
            const float* __restrict__ h_b,
            const float* __restrict__ P,   // exclusive chunk prefixes
            float* __restrict__ out) {
    int blk = blockIdx.x;
    int bg = blk / C;
    int c  = blk % C;
    int b0 = bg * BG;
    int tid = threadIdx.x;
    int h0 = tid * 4;
    int lane = tid & 63;
    int wv = tid >> 6;
    int ph = lane & 3;

    // x bitmasks for the two rows
    __shared__ unsigned mlds[BG];
    float xv = (tid < BG * L) ? x[(size_t)(b0 + (tid >> 5)) * D + c * L + (tid & 31)] : 0.f;
    unsigned long long bal = __ballot(xv != 0.f);
    if (tid == 0) { mlds[0] = (unsigned)bal; mlds[1] = (unsigned)(bal >> 32); }

    // a = prefix + in_b (per batch row)
    float4 ib = *reinterpret_cast<const float4*>(&in_b[h0]);
    float4 a0, a1;
    {
        float4 p0 = *reinterpret_cast<const float4*>(&P[((size_t)b0 * C + c) * H + h0]);
        float4 p1 = *reinterpret_cast<const float4*>(&P[((size_t)(b0 + 1) * C + c) * H + h0]);
        a0.x = p0.x + ib.x; a0.y = p0.y + ib.y; a0.z = p0.z + ib.z; a0.w = p0.w + ib.w;
        a1.x = p1.x + ib.x; a1.y = p1.y + ib.y; a1.z = p1.z + ib.z; a1.w = p1.w + ib.w;
    }

    __syncthreads();
    unsigned m0 = mlds[0], m1 = mlds[1];
    unsigned any = m0 | m1;

    float pr0[8], pr1[8];
    #pragma unroll
    for (int s = 0; s < 8; ++s) { pr0[s] = 0.f; pr1[s] = 0.f; }

    #pragma unroll
    for (int il = 0; il < L; ++il) {
        int i = c * L + il;
        float4 w = *reinterpret_cast<const float4*>(&h_W[(size_t)i * H + h0]);
        // row 0 dot partial
        float p0 = fmaxf(a0.x, 0.f) * w.x + fmaxf(a0.y, 0.f) * w.y +
                   fmaxf(a0.z, 0.f) * w.z + fmaxf(a0.w, 0.f) * w.w;
        float t0 = p0 + dpp_xor1(p0);
        t0 = t0 + dpp_xor2(t0);
        pr0[il >> 2] = (ph == (il & 3)) ? t0 : pr0[il >> 2];
        // row 1 dot partial
        float p1 = fmaxf(a1.x, 0.f) * w.x + fmaxf(a1.y, 0.f) * w.y +
                   fmaxf(a1.z, 0.f) * w.z + fmaxf(a1.w, 0.f) * w.w;
        float t1 = p1 + dpp_xor1(p1);
        t1 = t1 + dpp_xor2(t1);
        pr1[il >> 2] = (ph == (il & 3)) ? t1 : pr1[il >> 2];

        unsigned bit = 1u << il;
        if (any & bit) {   // wave-uniform
            float4 wv4 = *reinterpret_cast<const float4*>(&Wt[(size_t)i * H + h0]);
            if (m0 & bit) { a0.x += wv4.x; a0.y += wv4.y; a0.z += wv4.z; a0.w += wv4.w; }
            if (m1 & bit) { a1.x += wv4.x; a1.y += wv4.y; a1.z += wv4.z; a1.w += wv4.w; }
        }
    }

    // cross-quad reduce within the wave: after the butterflies every lane
    // holds the full wave-sum for il = s*4 + (lane&3)
    #pragma unroll
    for (int s = 0; s < 8; ++s) {
        float v0 = pr0[s];
        v0 += __shfl_xor(v0, 4, 64);
        v0 += __shfl_xor(v0, 8, 64);
        v0 += __shfl_xor(v0, 16, 64);
        v0 += __shfl_xor(v0, 32, 64);
        pr0[s] = v0;
        float v1 = pr1[s];
        v1 += __shfl_xor(v1, 4, 64);
        v1 += __shfl_xor(v1, 8, 64);
        v1 += __shfl_xor(v1, 16, 64);
        v1 += __shfl_xor(v1, 32, 64);
        pr1[s] = v1;
    }

    __shared__ float red[4][BG][L];
    if (lane < 4) {
        #pragma unroll
        for (int s = 0; s < 8; ++s) {
            red[wv][0][s * 4 + lane] = pr0[s];
            red[wv][1][s * 4 + lane] = pr1[s];
        }
    }
    __syncthreads();

    if (tid < BG * L) {
        int b = tid >> 5;
        int il = tid & 31;
        int i = c * L + il;
        float t = red[0][b][il] + red[1][b][il] + red[2][b][il] + red[3][b][il]
                + h_b[i];
        out[(size_t)(b0 + b) * D + i] = 1.0f / (1.0f + expf(-t));
    }
}

// ---------------------------------------------------------------------------
extern "C" void kernel_launch(void* const* d_in, const int* in_sizes, int n_in,
                              void* d_out, int out_size, void* d_ws, size_t ws_size,
                              hipStream_t stream) {
    const float* x    = (const float*)d_in[0];  // [B, D]
    const float* in_W = (const float*)d_in[1];  // [H, D]
    const float* in_b = (const float*)d_in[2];  // [H]
    const float* h_W  = (const float*)d_in[3];  // [D, H]
    const float* h_b  = (const float*)d_in[4];  // [D]
    float* out = (float*)d_out;                 // [B, D]

    float* Wt = (float*)d_ws;                   // [D, H]  4 MB
    float* S  = Wt + (size_t)D * H;             // [B, C, H]  8 MB

    // 0: transpose in_W -> Wt
    dim3 tb(32, 8);
    dim3 tg(D / 32, H / 32);
    k_transpose<<<tg, tb, 0, stream>>>(in_W, Wt);

    // 1: chunk sums (BG=2 register reuse)
    k_chunk_sums<<<NBG * C, 256, 0, stream>>>(x, Wt, S);

    // 2: exclusive scan over chunks (in place)
    k_scan<<<(B * H + 255) / 256, 256, 0, stream>>>(S);

    // 3: main serial chain (BG=2, barrier-free deferred reduction)
    k_nade_main<<<NBG * C, 256, 0, stream>>>(x, Wt, in_b, h_W, h_b, S, out);
}

// Round 5
// 47.300 us; speedup vs baseline: 1.0370x; 1.0370x over previous
//
#include <hip/hip_runtime.h>
#include <hip/hip_bf16.h>

// Problem constants
#define B 64
#define D 1024
#define H 1024
#define C 32           // number of chunks along D
#define L (D / C)      // chunk length = 32

// DPP quad-perm cross-lane (VALU-speed, no LDS)
__device__ __forceinline__ float dpp_xor1(float v) {
    int i = __builtin_bit_cast(int, v);
    i = __builtin_amdgcn_mov_dpp(i, 0xB1, 0xF, 0xF, true);  // quad_perm [1,0,3,2]
    return __builtin_bit_cast(float, i);
}
__device__ __forceinline__ float dpp_xor2(float v) {
    int i = __builtin_bit_cast(int, v);
    i = __builtin_amdgcn_mov_dpp(i, 0x4E, 0xF, 0xF, true);  // quad_perm [2,3,0,1]
    return __builtin_bit_cast(float, i);
}

// ---------------------------------------------------------------------------
// Kernel 0: transpose in_W [H, D] -> Wt [D, H]
// ---------------------------------------------------------------------------
__global__ void k_transpose(const float* __restrict__ in, float* __restrict__ out) {
    __shared__ float tile[32][33];
    int bx = blockIdx.x * 32;  // d-range
    int by = blockIdx.y * 32;  // h-range
    int tx = threadIdx.x;      // 0..31
    int ty = threadIdx.y;      // 0..7
    #pragma unroll
    for (int r = 0; r < 32; r += 8)
        tile[ty + r][tx] = in[(by + ty + r) * D + (bx + tx)];
    __syncthreads();
    #pragma unroll
    for (int r = 0; r < 32; r += 8)
        out[(bx + ty + r) * H + (by + tx)] = tile[tx][ty + r];
}

// ---------------------------------------------------------------------------
// Kernel 1: per-chunk rank-1 sums. block = (b,c), 256 threads, 4 h per thread.
// Branch-free: acc += x_j * Wt[j,:]  (x is exactly {0,1} -> predicated FMA)
// ---------------------------------------------------------------------------
__global__ void __launch_bounds__(256, 4)
k_chunk_sums(const float* __restrict__ x,
             const float* __restrict__ Wt,
             float* __restrict__ S) {
    int blk = blockIdx.x;
    int b = blk / C;
    int c = blk % C;
    int tid = threadIdx.x;
    int h0 = tid * 4;

    __shared__ float xs[L];
    if (tid < L) xs[tid] = x[(size_t)b * D + c * L + tid];
    __syncthreads();

    float4 acc = make_float4(0.f, 0.f, 0.f, 0.f);
    #pragma unroll
    for (int j = 0; j < L; ++j) {
        float xf = xs[j];   // LDS broadcast, {0,1}
        float4 w = *reinterpret_cast<const float4*>(&Wt[(size_t)(c * L + j) * H + h0]);
        acc.x = fmaf(xf, w.x, acc.x);
        acc.y = fmaf(xf, w.y, acc.y);
        acc.z = fmaf(xf, w.z, acc.z);
        acc.w = fmaf(xf, w.w, acc.w);
    }
    *reinterpret_cast<float4*>(&S[((size_t)b * C + c) * H + h0]) = acc;
}

// ---------------------------------------------------------------------------
// Kernel 2: in-place exclusive scan over chunks
// ---------------------------------------------------------------------------
__global__ void k_scan(float* __restrict__ S) {
    int tid = blockIdx.x * blockDim.x + threadIdx.x;  // 0 .. B*H-1
    if (tid >= B * H) return;
    int b = tid / H;
    int h = tid % H;
    float run = 0.f;
    #pragma unroll
    for (int c = 0; c < C; ++c) {
        int idx = (b * C + c) * H + h;
        float v = S[idx];
        S[idx] = run;
        run += v;
    }
}

// ---------------------------------------------------------------------------
// Kernel 3: main NADE chain. block = (b,c), 256 threads, 4 h per thread.
// Fully branch-free inner loop: unconditional h_W/Wt loads, predicated FMA
// recurrence (x in {0,1}), quad-DPP reduce + keeper-lane register stash.
// All cross-quad/cross-wave reduction + sigmoid happen once after the loop.
// ---------------------------------------------------------------------------
__global__ void __launch_bounds__(256, 4)
k_nade_main(const float* __restrict__ x,
            const float* __restrict__ Wt,
            const float* __restrict__ in_b,
            const float* __restrict__ h_W,
            const float* __restrict__ h_b,
            const float* __restrict__ P,   // exclusive chunk prefixes
            float* __restrict__ out) {
    int blk = blockIdx.x;
    int b = blk / C;
    int c = blk % C;
    int tid = threadIdx.x;
    int h0 = tid * 4;
    int lane = tid & 63;
    int wv = tid >> 6;
    int ph = lane & 3;

    __shared__ float xs[L];
    if (tid < L) xs[tid] = x[(size_t)b * D + c * L + tid];

    // a = prefix + in_b
    float4 pv = *reinterpret_cast<const float4*>(&P[((size_t)b * C + c) * H + h0]);
    float4 ib = *reinterpret_cast<const float4*>(&in_b[h0]);
    float4 a;
    a.x = pv.x + ib.x; a.y = pv.y + ib.y; a.z = pv.z + ib.z; a.w = pv.w + ib.w;

    __syncthreads();

    float pr[8];
    #pragma unroll
    for (int s = 0; s < 8; ++s) pr[s] = 0.f;

    #pragma unroll
    for (int il = 0; il < L; ++il) {
        int i = c * L + il;
        float4 w = *reinterpret_cast<const float4*>(&h_W[(size_t)i * H + h0]);
        float p = fmaxf(a.x, 0.f) * w.x + fmaxf(a.y, 0.f) * w.y +
                  fmaxf(a.z, 0.f) * w.z + fmaxf(a.w, 0.f) * w.w;
        // quad (4-lane) reduce, VALU-only
        float t = p + dpp_xor1(p);
        t = t + dpp_xor2(t);
        // keeper lane (ph == il&3) stashes the quad-sum for this il
        pr[il >> 2] = (ph == (il & 3)) ? t : pr[il >> 2];

        // branch-free recurrence: a += x_i * Wt[i,:]
        float xf = xs[il];   // LDS broadcast, {0,1}
        float4 wv4 = *reinterpret_cast<const float4*>(&Wt[(size_t)i * H + h0]);
        a.x = fmaf(xf, wv4.x, a.x);
        a.y = fmaf(xf, wv4.y, a.y);
        a.z = fmaf(xf, wv4.z, a.z);
        a.w = fmaf(xf, wv4.w, a.w);
    }

    // cross-quad reduce within the wave: after the butterflies every lane
    // holds the full wave-sum for il = s*4 + (lane&3)
    #pragma unroll
    for (int s = 0; s < 8; ++s) {
        float v = pr[s];
        v += __shfl_xor(v, 4, 64);
        v += __shfl_xor(v, 8, 64);
        v += __shfl_xor(v, 16, 64);
        v += __shfl_xor(v, 32, 64);
        pr[s] = v;
    }

    __shared__ float red[4][L];
    if (lane < 4) {
        #pragma unroll
        for (int s = 0; s < 8; ++s)
            red[wv][s * 4 + lane] = pr[s];
    }
    __syncthreads();

    if (tid < L) {
        int i = c * L + tid;
        float t = red[0][tid] + red[1][tid] + red[2][tid] + red[3][tid] + h_b[i];
        out[(size_t)b * D + i] = 1.0f / (1.0f + expf(-t));
    }
}

// ---------------------------------------------------------------------------
extern "C" void kernel_launch(void* const* d_in, const int* in_sizes, int n_in,
                              void* d_out, int out_size, void* d_ws, size_t ws_size,
                              hipStream_t stream) {
    const float* x    = (const float*)d_in[0];  // [B, D]
    const float* in_W = (const float*)d_in[1];  // [H, D]
    const float* in_b = (const float*)d_in[2];  // [H]
    const float* h_W  = (const float*)d_in[3];  // [D, H]
    const float* h_b  = (const float*)d_in[4];  // [D]
    float* out = (float*)d_out;                 // [B, D]

    float* Wt = (float*)d_ws;                   // [D, H]  4 MB
    float* S  = Wt + (size_t)D * H;             // [B, C, H]  8 MB

    // 0: transpose in_W -> Wt
    dim3 tb(32, 8);
    dim3 tg(D / 32, H / 32);
    k_transpose<<<tg, tb, 0, stream>>>(in_W, Wt);

    // 1: chunk sums (branch-free predicated FMA)
    k_chunk_sums<<<B * C, 256, 0, stream>>>(x, Wt, S);

    // 2: exclusive scan over chunks (in place)
    k_scan<<<(B * H + 255) / 256, 256, 0, stream>>>(S);

    // 3: main serial chain (branch-free, deferred reduction)
    k_nade_main<<<B * C, 256, 0, stream>>>(x, Wt, in_b, h_W, h_b, S, out);
}

// Round 6
// 41.201 us; speedup vs baseline: 1.1905x; 1.1480x over previous
//
#include <hip/hip_runtime.h>
#include <hip/hip_bf16.h>

// Problem constants
#define B 64
#define D 1024
#define H 1024
#define C 32           // chunks along D
#define L (D / C)      // chunk length = 32
#define BG 4           // batch rows per block (register-shared weight loads)
#define NBG (B / BG)   // 16 batch groups
#define HQ 4           // h-quarters per row
#define HP (H / HQ)    // 256 h per block = 1 h per thread

// DPP quad-perm cross-lane (VALU-speed, no LDS)
__device__ __forceinline__ float dpp_xor1(float v) {
    int i = __builtin_bit_cast(int, v);
    i = __builtin_amdgcn_mov_dpp(i, 0xB1, 0xF, 0xF, true);  // quad_perm [1,0,3,2]
    return __builtin_bit_cast(float, i);
}
__device__ __forceinline__ float dpp_xor2(float v) {
    int i = __builtin_bit_cast(int, v);
    i = __builtin_amdgcn_mov_dpp(i, 0x4E, 0xF, 0xF, true);  // quad_perm [2,3,0,1]
    return __builtin_bit_cast(float, i);
}

// ---------------------------------------------------------------------------
// Kernel 0: transpose in_W [H, D] -> Wt [D, H]
// ---------------------------------------------------------------------------
__global__ void k_transpose(const float* __restrict__ in, float* __restrict__ out) {
    __shared__ float tile[32][33];
    int bx = blockIdx.x * 32;  // d-range
    int by = blockIdx.y * 32;  // h-range
    int tx = threadIdx.x;      // 0..31
    int ty = threadIdx.y;      // 0..7
    #pragma unroll
    for (int r = 0; r < 32; r += 8)
        tile[ty + r][tx] = in[(by + ty + r) * D + (bx + tx)];
    __syncthreads();
    #pragma unroll
    for (int r = 0; r < 32; r += 8)
        out[(bx + ty + r) * H + (by + tx)] = tile[tx][ty + r];
}

// ---------------------------------------------------------------------------
// Kernel 1: per-chunk rank-1 sums. block = (bg, c, hq): 4 batch rows share
// each Wt dword in registers. 256 threads = 1 h each.
// S[b,c,h] = sum_{j in chunk c} x[b,j]*Wt[j,h]   (x exactly {0,1})
// ---------------------------------------------------------------------------
__global__ void __launch_bounds__(256)
k_chunk_sums(const float* __restrict__ x,
             const float* __restrict__ Wt,
             float* __restrict__ S) {
    int blk = blockIdx.x;
    int bg  = blk >> 7;          // /128
    int chq = blk & 127;
    int c   = chq >> 2;
    int hq  = chq & 3;
    int b0  = bg * BG;
    int tid = threadIdx.x;
    int h   = hq * HP + tid;

    __shared__ float4 xs4[L];
    if (tid < L) {
        int i = c * L + tid;
        xs4[tid] = make_float4(x[(size_t)b0 * D + i],
                               x[(size_t)(b0 + 1) * D + i],
                               x[(size_t)(b0 + 2) * D + i],
                               x[(size_t)(b0 + 3) * D + i]);
    }
    __syncthreads();

    float acc0 = 0.f, acc1 = 0.f, acc2 = 0.f, acc3 = 0.f;
    #pragma unroll
    for (int j = 0; j < L; ++j) {
        float w = Wt[(size_t)(c * L + j) * H + h];
        float4 xf = xs4[j];
        acc0 = fmaf(xf.x, w, acc0);
        acc1 = fmaf(xf.y, w, acc1);
        acc2 = fmaf(xf.z, w, acc2);
        acc3 = fmaf(xf.w, w, acc3);
    }
    S[((size_t)b0 * C + c) * H + h]       = acc0;
    S[((size_t)(b0 + 1) * C + c) * H + h] = acc1;
    S[((size_t)(b0 + 2) * C + c) * H + h] = acc2;
    S[((size_t)(b0 + 3) * C + c) * H + h] = acc3;
}

// ---------------------------------------------------------------------------
// Kernel 2: in-place exclusive scan over chunks
// ---------------------------------------------------------------------------
__global__ void k_scan(float* __restrict__ S) {
    int tid = blockIdx.x * blockDim.x + threadIdx.x;  // 0 .. B*H-1
    if (tid >= B * H) return;
    int b = tid / H;
    int h = tid % H;
    float run = 0.f;
    #pragma unroll
    for (int c = 0; c < C; ++c) {
        int idx = (b * C + c) * H + h;
        float v = S[idx];
        S[idx] = run;
        run += v;
    }
}

// ---------------------------------------------------------------------------
// Kernel 3: main NADE chain. block = (bg, c, hq); 256 threads = 1 h each;
// 4 batch rows per thread share every h_W/Wt dword. Barrier-free inner loop:
// scalar dot partial per row, quad-DPP reduce, keeper-lane stash; predicated
// FMA recurrence. Writes per-quarter partial dots to Q[hq][b][d].
// ---------------------------------------------------------------------------
__global__ void __launch_bounds__(256)
k_nade_main(const float* __restrict__ x,
            const float* __restrict__ Wt,
            const float* __restrict__ in_b,
            const float* __restrict__ h_W,
            const float* __restrict__ h_b,
            const float* __restrict__ P,   // exclusive chunk prefixes
            float* __restrict__ Q) {       // [HQ][B][D] partial dots
    int blk = blockIdx.x;
    int bg  = blk >> 7;
    int chq = blk & 127;
    int c   = chq >> 2;
    int hq  = chq & 3;
    int b0  = bg * BG;
    int tid = threadIdx.x;
    int h   = hq * HP + tid;
    int lane = tid & 63;
    int wv = tid >> 6;
    int ph = lane & 3;

    __shared__ float4 xs4[L];
    if (tid < L) {
        int i = c * L + tid;
        xs4[tid] = make_float4(x[(size_t)b0 * D + i],
                               x[(size_t)(b0 + 1) * D + i],
                               x[(size_t)(b0 + 2) * D + i],
                               x[(size_t)(b0 + 3) * D + i]);
    }

    float ib = in_b[h];
    float a0 = P[((size_t)b0 * C + c) * H + h] + ib;
    float a1 = P[((size_t)(b0 + 1) * C + c) * H + h] + ib;
    float a2 = P[((size_t)(b0 + 2) * C + c) * H + h] + ib;
    float a3 = P[((size_t)(b0 + 3) * C + c) * H + h] + ib;

    __syncthreads();

    // keeper masks (which il%4 this lane stashes)
    bool k0 = (ph == 0), k1 = (ph == 1), k2 = (ph == 2), k3 = (ph == 3);

    float pr0[8], pr1[8], pr2[8], pr3[8];
    #pragma unroll
    for (int s = 0; s < 8; ++s) { pr0[s] = 0.f; pr1[s] = 0.f; pr2[s] = 0.f; pr3[s] = 0.f; }

    #pragma unroll
    for (int il = 0; il < L; ++il) {
        int i = c * L + il;
        float w  = h_W[(size_t)i * H + h];
        float wt = Wt[(size_t)i * H + h];
        float4 xf = xs4[il];
        int s = il >> 2;
        bool keep = (il & 3) == 0 ? k0 : ((il & 3) == 1 ? k1 : ((il & 3) == 2 ? k2 : k3));

        float p0 = fmaxf(a0, 0.f) * w;
        float t0 = p0 + dpp_xor1(p0); t0 = t0 + dpp_xor2(t0);
        pr0[s] = keep ? t0 : pr0[s];
        a0 = fmaf(xf.x, wt, a0);

        float p1 = fmaxf(a1, 0.f) * w;
        float t1 = p1 + dpp_xor1(p1); t1 = t1 + dpp_xor2(t1);
        pr1[s] = keep ? t1 : pr1[s];
        a1 = fmaf(xf.y, wt, a1);

        float p2 = fmaxf(a2, 0.f) * w;
        float t2 = p2 + dpp_xor1(p2); t2 = t2 + dpp_xor2(t2);
        pr2[s] = keep ? t2 : pr2[s];
        a2 = fmaf(xf.z, wt, a2);

        float p3 = fmaxf(a3, 0.f) * w;
        float t3 = p3 + dpp_xor1(p3); t3 = t3 + dpp_xor2(t3);
        pr3[s] = keep ? t3 : pr3[s];
        a3 = fmaf(xf.w, wt, a3);
    }

    // cross-quad reduce within the wave (sum over 16 quads = 64 h)
    #pragma unroll
    for (int s = 0; s < 8; ++s) {
        float v;
        v = pr0[s];
        v += __shfl_xor(v, 4, 64); v += __shfl_xor(v, 8, 64);
        v += __shfl_xor(v, 16, 64); v += __shfl_xor(v, 32, 64);
        pr0[s] = v;
        v = pr1[s];
        v += __shfl_xor(v, 4, 64); v += __shfl_xor(v, 8, 64);
        v += __shfl_xor(v, 16, 64); v += __shfl_xor(v, 32, 64);
        pr1[s] = v;
        v = pr2[s];
        v += __shfl_xor(v, 4, 64); v += __shfl_xor(v, 8, 64);
        v += __shfl_xor(v, 16, 64); v += __shfl_xor(v, 32, 64);
        pr2[s] = v;
        v = pr3[s];
        v += __shfl_xor(v, 4, 64); v += __shfl_xor(v, 8, 64);
        v += __shfl_xor(v, 16, 64); v += __shfl_xor(v, 32, 64);
        pr3[s] = v;
    }

    __shared__ float red[4][BG][L];
    if (lane < 4) {
        #pragma unroll
        for (int s = 0; s < 8; ++s) {
            red[wv][0][s * 4 + lane] = pr0[s];
            red[wv][1][s * 4 + lane] = pr1[s];
            red[wv][2][s * 4 + lane] = pr2[s];
            red[wv][3][s * 4 + lane] = pr3[s];
        }
    }
    __syncthreads();

    if (tid < BG * L) {
        int b = tid >> 5;
        int il = tid & 31;
        float t = red[0][b][il] + red[1][b][il] + red[2][b][il] + red[3][b][il];
        Q[((size_t)hq * B + (b0 + b)) * D + c * L + il] = t;
    }
}

// ---------------------------------------------------------------------------
// Kernel 4: combine h-quarter partials + bias + sigmoid
// ---------------------------------------------------------------------------
__global__ void __launch_bounds__(256)
k_combine(const float* __restrict__ Q,
          const float* __restrict__ h_b,
          float* __restrict__ out) {
    int idx = blockIdx.x * blockDim.x + threadIdx.x;  // 0 .. B*D-1
    if (idx >= B * D) return;
    int d = idx & (D - 1);
    float t = Q[idx] + Q[(size_t)B * D + idx] + Q[2 * (size_t)B * D + idx]
            + Q[3 * (size_t)B * D + idx] + h_b[d];
    out[idx] = 1.0f / (1.0f + expf(-t));
}

// ---------------------------------------------------------------------------
extern "C" void kernel_launch(void* const* d_in, const int* in_sizes, int n_in,
                              void* d_out, int out_size, void* d_ws, size_t ws_size,
                              hipStream_t stream) {
    const float* x    = (const float*)d_in[0];  // [B, D]
    const float* in_W = (const float*)d_in[1];  // [H, D]
    const float* in_b = (const float*)d_in[2];  // [H]
    const float* h_W  = (const float*)d_in[3];  // [D, H]
    const float* h_b  = (const float*)d_in[4];  // [D]
    float* out = (float*)d_out;                 // [B, D]

    float* Wt = (float*)d_ws;                   // [D, H]        4 MB
    float* S  = Wt + (size_t)D * H;             // [B, C, H]     8 MB
    float* Q  = S + (size_t)B * C * H;          // [HQ, B, D]    1 MB

    // 0: transpose in_W -> Wt
    dim3 tb(32, 8);
    dim3 tg(D / 32, H / 32);
    k_transpose<<<tg, tb, 0, stream>>>(in_W, Wt);

    // 1: chunk sums (BG=4 register reuse, h-quarter split)
    k_chunk_sums<<<NBG * C * HQ, 256, 0, stream>>>(x, Wt, S);

    // 2: exclusive scan over chunks (in place)
    k_scan<<<(B * H + 255) / 256, 256, 0, stream>>>(S);

    // 3: main serial chain (BG=4, h-quarter split, barrier-free)
    k_nade_main<<<NBG * C * HQ, 256, 0, stream>>>(x, Wt, in_b, h_W, h_b, S, Q);

    // 4: combine quarters + sigmoid
    k_combine<<<(B * D + 255) / 256, 256, 0, stream>>>(Q, h_b, out);
}